// Round 15
// baseline (1630.413 us; speedup 1.0000x reference)
//
#include <hip/hip_runtime.h>

// ---------------------------------------------------------------------------
// NeuronCircuitQKV round 15: r14 + FULL GEMM half-tile counted waits.
// Stage split: h0={Ah,Bh} issued at iteration top, h1={Al,Bl} at bottom.
// Per step: vmcnt(8) -> hh-compute (h1 still in flight) -> vmcnt(4)+bar ->
// hl+lh compute (a_h/b_h reg-carried). Tail waits 4/0. One extra barrier.
// FAST (BK=64) / attn / routers / reflects byte-identical to r14 (1618us).
// Precision locked: 3-MFMA split-fp16 pre-router; 1-MFMA post-router.
// ---------------------------------------------------------------------------

typedef __attribute__((ext_vector_type(4))) float f32x4;
typedef _Float16 f16x8 __attribute__((ext_vector_type(8)));
typedef _Float16 f16x4 __attribute__((ext_vector_type(4)));

static constexpr int S_LEN  = 2048;
static constexpr int TOK    = 4096;   // B*S
static constexpr int DMODEL = 1024;
static constexpr int KDIM   = 8192;   // 8 experts * 1024

__device__ __forceinline__ void async16(const void* g, void* l) {
  __builtin_amdgcn_global_load_lds(
      (const __attribute__((address_space(1))) void*)g,
      (__attribute__((address_space(3))) void*)l, 16, 0, 0);
}

// ---------------------------------------------------------------------------
// Transpose (KDIM x DMODEL fp32) -> (DMODEL x KDIM fp16 hi[/lo] planes).
// ---------------------------------------------------------------------------
__global__ __launch_bounds__(256) void transpose_split(const float* __restrict__ W,
                                                       _Float16* __restrict__ Th,
                                                       _Float16* __restrict__ Tl) {
  __shared__ float tbuf[64][65];
  const int tid = threadIdx.x;
  const int k0 = blockIdx.x * 64, n0 = blockIdx.y * 64;
#pragma unroll
  for (int j = 0; j < 4; ++j) {
    int ci = tid + 256 * j;
    int r = ci >> 4, c4 = (ci & 15) * 4;
    float4 v = *(const float4*)&W[(size_t)(k0 + r) * DMODEL + n0 + c4];
    tbuf[r][c4 + 0] = v.x; tbuf[r][c4 + 1] = v.y;
    tbuf[r][c4 + 2] = v.z; tbuf[r][c4 + 3] = v.w;
  }
  __syncthreads();
#pragma unroll
  for (int j = 0; j < 2; ++j) {
    int ci = tid + 256 * j;
    int nl = ci >> 3, k8 = (ci & 7) * 8;
    f16x8 hv, lv;
#pragma unroll
    for (int e = 0; e < 8; ++e) {
      float v = tbuf[k8 + e][nl];
      _Float16 hh = (_Float16)v;
      hv[e] = hh;
      lv[e] = (_Float16)(v - (float)hh);
    }
    size_t off = (size_t)(n0 + nl) * KDIM + k0 + k8;
    *(f16x8*)&Th[off] = hv;
    if (Tl != nullptr) *(f16x8*)&Tl[off] = lv;
  }
}

// ---------------------------------------------------------------------------
// Router: 48 logits (fp64 accum -> stable top-k), softmaxes, top-3.
// ---------------------------------------------------------------------------
__global__ __launch_bounds__(256) void router_kernel(const float* __restrict__ X,
                                                     const float* __restrict__ Wi,
                                                     const float* __restrict__ Wp,
                                                     const float* __restrict__ Wo,
                                                     float* __restrict__ in_w,
                                                     float* __restrict__ out_w,
                                                     int* __restrict__ pidx,
                                                     _Float16* __restrict__ Xh,
                                                     _Float16* __restrict__ Xl) {
  __shared__ float xs[1024];
  __shared__ double lg[48];
  const int t = blockIdx.x, tid = threadIdx.x;
  const int wid = tid >> 6, lane = tid & 63;
#pragma unroll
  for (int j = 0; j < 4; ++j) {
    int d = tid + 256 * j;
    xs[d] = X[(size_t)t * DMODEL + d];
  }
  __syncthreads();
  for (int i = wid; i < 48; i += 4) {
    const float* wrow = (i < 8)  ? Wi + (size_t)i * DMODEL
                      : (i < 40) ? Wp + (size_t)(i - 8) * DMODEL
                                 : Wo + (size_t)(i - 40) * DMODEL;
    double s = 0.0;
#pragma unroll
    for (int j = 0; j < 16; ++j) { int d = lane + 64 * j; s += (double)xs[d] * (double)wrow[d]; }
#pragma unroll
    for (int mm = 32; mm >= 1; mm >>= 1) s += __shfl_xor(s, mm);
    if (lane == 0) lg[i] = s;
  }
  __syncthreads();
  if (tid == 0) {
    float l[8], m;
    for (int i = 0; i < 8; ++i) l[i] = (float)lg[i];
    m = l[0];
    for (int i = 1; i < 8; ++i) m = fmaxf(m, l[i]);
    float e[8], su = 0.f;
    for (int i = 0; i < 8; ++i) { e[i] = expf(l[i] - m); su += e[i]; }
    for (int i = 0; i < 8; ++i) in_w[t * 8 + i] = e[i] / su;
  } else if (tid == 64) {
    float l[8], m;
    for (int i = 0; i < 8; ++i) l[i] = (float)lg[40 + i];
    m = l[0];
    for (int i = 1; i < 8; ++i) m = fmaxf(m, l[i]);
    float e[8], su = 0.f;
    for (int i = 0; i < 8; ++i) { e[i] = expf(l[i] - m); su += e[i]; }
    for (int i = 0; i < 8; ++i) out_w[t * 8 + i] = e[i] / su;
  } else if (tid == 128) {
    unsigned used = 0;
    for (int j = 0; j < 3; ++j) {
      double best = -1e300; int bi = 0;
      for (int i = 0; i < 32; ++i)
        if (!((used >> i) & 1u) && lg[8 + i] > best) { best = lg[8 + i]; bi = i; }
      used |= 1u << bi;
      pidx[t * 3 + j] = bi;
    }
  }
  if (Xh != nullptr) {
#pragma unroll
    for (int j = 0; j < 4; ++j) {
      int d = tid + 256 * j;
      float v = xs[d];
      _Float16 hh = (_Float16)v;
      Xh[(size_t)t * DMODEL + d] = hh;
      Xl[(size_t)t * DMODEL + d] = (_Float16)(v - (float)hh);
    }
  }
}

// ---------------------------------------------------------------------------
// h = Pa+Pb+Pc+Pd, 3 Householder reflections, write fp16 hi/lo planes.
// ---------------------------------------------------------------------------
__global__ __launch_bounds__(256) void reflect4_kernel(const float* __restrict__ Pa,
                                                       const float* __restrict__ Pb,
                                                       const float* __restrict__ Pc,
                                                       const float* __restrict__ Pd,
                                                       const int* __restrict__ pidx,
                                                       const float* __restrict__ vtab,
                                                       _Float16* __restrict__ Hh,
                                                       _Float16* __restrict__ Hl) {
  __shared__ float red[8];
  const int t = blockIdx.x, tid = threadIdx.x;
  const int wid = tid >> 6, lane = tid & 63;
  size_t gi = (size_t)t * DMODEL + tid * 4;
  float4 ha = *(const float4*)&Pa[gi];
  float4 hb = *(const float4*)&Pb[gi];
  float4 hc = *(const float4*)&Pc[gi];
  float4 hd = *(const float4*)&Pd[gi];
  float4 h = {ha.x + hb.x + hc.x + hd.x, ha.y + hb.y + hc.y + hd.y,
              ha.z + hb.z + hc.z + hd.z, ha.w + hb.w + hc.w + hd.w};
  for (int i = 0; i < 3; ++i) {
    int idx = pidx[t * 3 + i];
    float4 vi = *(const float4*)&vtab[(size_t)idx * DMODEL + tid * 4];
    float hv = h.x * vi.x + h.y * vi.y + h.z * vi.z + h.w * vi.w;
    float vv = vi.x * vi.x + vi.y * vi.y + vi.z * vi.z + vi.w * vi.w;
#pragma unroll
    for (int mm = 32; mm >= 1; mm >>= 1) { hv += __shfl_xor(hv, mm); vv += __shfl_xor(vv, mm); }
    if (lane == 0) { red[wid] = hv; red[4 + wid] = vv; }
    __syncthreads();
    float dot = red[0] + red[1] + red[2] + red[3];
    float vn  = red[4] + red[5] + red[6] + red[7];
    __syncthreads();
    float c = 2.f * dot / (vn + 1e-8f);
    h.x -= c * vi.x; h.y -= c * vi.y; h.z -= c * vi.z; h.w -= c * vi.w;
  }
  float a[4] = {h.x, h.y, h.z, h.w};
  f16x4 hv4, lv4;
#pragma unroll
  for (int e = 0; e < 4; ++e) {
    _Float16 hh = (_Float16)a[e];
    hv4[e] = hh;
    lv4[e] = (_Float16)(a[e] - (float)hh);
  }
  *(f16x4*)&Hh[gi] = hv4;
  *(f16x4*)&Hl[gi] = lv4;
}

// ---------------------------------------------------------------------------
// 4-way reduce -> fp16 hi/lo planes (for Q/K). grid 4096, blk 256.
// ---------------------------------------------------------------------------
__global__ __launch_bounds__(256) void reduce4_planes(const float* __restrict__ a,
                                                      const float* __restrict__ b,
                                                      const float* __restrict__ c,
                                                      const float* __restrict__ d,
                                                      _Float16* __restrict__ Dh,
                                                      _Float16* __restrict__ Dl) {
  size_t i = ((size_t)blockIdx.x * 256 + threadIdx.x) * 4;
  float4 va = *(const float4*)&a[i];
  float4 vb = *(const float4*)&b[i];
  float4 vc = *(const float4*)&c[i];
  float4 vd = *(const float4*)&d[i];
  float s[4] = {va.x + vb.x + vc.x + vd.x, va.y + vb.y + vc.y + vd.y,
                va.z + vb.z + vc.z + vd.z, va.w + vb.w + vc.w + vd.w};
  f16x4 hv, lv;
#pragma unroll
  for (int e = 0; e < 4; ++e) {
    _Float16 hh = (_Float16)s[e];
    hv[e] = hh;
    lv[e] = (_Float16)(s[e] - (float)hh);
  }
  *(f16x4*)&Dh[i] = hv;
  *(f16x4*)&Dl[i] = lv;
}

// ---------------------------------------------------------------------------
// 4-way reduce -> fp32 (final output). grid 4096, blk 256.
// ---------------------------------------------------------------------------
__global__ __launch_bounds__(256) void reduce4_f32(const float* __restrict__ a,
                                                   const float* __restrict__ b,
                                                   const float* __restrict__ c,
                                                   const float* __restrict__ d,
                                                   float* __restrict__ o) {
  size_t i = ((size_t)blockIdx.x * 256 + threadIdx.x) * 4;
  float4 va = *(const float4*)&a[i];
  float4 vb = *(const float4*)&b[i];
  float4 vc = *(const float4*)&c[i];
  float4 vd = *(const float4*)&d[i];
  float4 vo = {va.x + vb.x + vc.x + vd.x, va.y + vb.y + vc.y + vd.y,
               va.z + vb.z + vc.z + vd.z, va.w + vb.w + vc.w + vd.w};
  *(float4*)&o[i] = vo;
}

// ---------------------------------------------------------------------------
// Split-fp16 GEMM, 256x256 tiles, balanced split-K=4, dbuf + half-tile
// counted waits. FULL: BK=32, h0={Ah,Bh} issued at top / h1={Al,Bl} at
// bottom; per step vmcnt(8) -> 32 hh-MFMA -> vmcnt(4)+bar -> 64 hl+lh MFMA
// (a_h/b_h reg-carried). FAST (r14-identical): BK=64, 1 MFMA, vmcnt(8).
// 8 waves (2Mx4N), wave tile 128x64. Grid (16,4,4) = 1 block/CU, XCD remap.
// ---------------------------------------------------------------------------
template <bool FAST>
__global__ __launch_bounds__(512, 2) void gemm_planes(const _Float16* __restrict__ Ahp,
                                                      const _Float16* __restrict__ Alp,
                                                      const float* __restrict__ wmix,
                                                      const _Float16* __restrict__ Bh,
                                                      const _Float16* __restrict__ Bl,
                                                      float* __restrict__ C0,
                                                      float* __restrict__ C1,
                                                      float* __restrict__ C2,
                                                      float* __restrict__ C3) {
  constexpr int BK     = FAST ? 64 : 32;
  constexpr int NSTEPS = 2048 / BK;          // 32 (FAST) or 64 (FULL)
  __shared__ _Float16 sAh[2][256 * BK];
  __shared__ _Float16 sBh[2][256 * BK];
  __shared__ _Float16 sAl[2][FAST ? 8 : 256 * 32];
  __shared__ _Float16 sBl[2][FAST ? 8 : 256 * 32];
  __shared__ float sWr[256 * 2];   // [row][0]=w0/w1 (boundary), [row][1]=w1
  const int tid = threadIdx.x;              // 0..511
  const int wid = tid >> 6, lane = tid & 63;
  const int l16 = lane & 15, lhi = lane >> 4;
  const int wr = wid >> 2, wc = wid & 3;    // 2 x 4 wave grid
  // Bijective XCD remap: 256 wgs, 32/XCD.
  const int fid = blockIdx.x + (blockIdx.y << 4) + (blockIdx.z << 6);
  const int wg  = ((fid & 7) << 5) + (fid >> 3);
  const int bm = (wg & 15) * 256;
  const int bn = ((wg >> 4) & 3) * 256;
  const int kz = wg >> 6;                   // 0..3
  const int kbase = kz * 2048, nb = kz * 2;
  float* __restrict__ Cp = (kz == 0) ? C0 : (kz == 1) ? C1 : (kz == 2) ? C2 : C3;

  {
    int row = tid >> 1, p = tid & 1;
    const float* w = &wmix[(size_t)(bm + row) * 8 + nb];
    sWr[tid] = p ? w[1] : w[0] / w[1];
  }

  f32x4 acc[8][4];
#pragma unroll
  for (int i = 0; i < 8; ++i)
#pragma unroll
    for (int j = 0; j < 4; ++j) { f32x4 z = {0.f, 0.f, 0.f, 0.f}; acc[i][j] = z; }

  // FULL half-stages: h0 = {Ah, Bh} (4 loads), h1 = {Al, Bl} (4 loads).
  auto STAGE_H0 = [&](int buf, int kt) {
    const int kg = kbase + kt, d0 = kg & 1023;
#pragma unroll
    for (int j = 0; j < 2; ++j) {
      int ci = tid + 512 * j;
      int row = ci >> 2, jc = ci & 3;
      int jcs = jc ^ ((row >> 1) & 3);
      size_t ga = (size_t)(bm + row) * DMODEL + d0 + jcs * 8;
      size_t gb = (size_t)(bn + row) * KDIM + kg + jcs * 8;
      async16(&Ahp[ga], &sAh[buf][ci * 8]);
      async16(&Bh[gb],  &sBh[buf][ci * 8]);
    }
  };
  auto STAGE_H1 = [&](int buf, int kt) {
    const int kg = kbase + kt, d0 = kg & 1023;
#pragma unroll
    for (int j = 0; j < 2; ++j) {
      int ci = tid + 512 * j;
      int row = ci >> 2, jc = ci & 3;
      int jcs = jc ^ ((row >> 1) & 3);
      size_t ga = (size_t)(bm + row) * DMODEL + d0 + jcs * 8;
      size_t gb = (size_t)(bn + row) * KDIM + kg + jcs * 8;
      async16(&Alp[ga], &sAl[buf][ci * 8]);
      async16(&Bl[gb],  &sBl[buf][ci * 8]);
    }
  };
  auto STAGE_FAST = [&](int buf, int kt) {   // BK=64, {Ah,Bh}, row&7 swizzle
    const int kg = kbase + kt, d0 = kg & 1023;
#pragma unroll
    for (int j = 0; j < 4; ++j) {
      int ci = tid + 512 * j;
      int row = ci >> 3, jc = ci & 7;
      int jcs = jc ^ (row & 7);
      size_t ga = (size_t)(bm + row) * DMODEL + d0 + jcs * 8;
      size_t gb = (size_t)(bn + row) * KDIM + kg + jcs * 8;
      async16(&Ahp[ga], &sAh[buf][ci * 8]);
      async16(&Bh[gb],  &sBh[buf][ci * 8]);
    }
  };

  auto RESCALE = [&]() {
#pragma unroll
    for (int mi = 0; mi < 8; ++mi)
#pragma unroll
      for (int r = 0; r < 4; ++r) {
        float s = sWr[(wr * 128 + mi * 16 + lhi * 4 + r) * 2];
#pragma unroll
        for (int ni = 0; ni < 4; ++ni) acc[mi][ni][r] *= s;
      }
  };

  if constexpr (FAST) {
    STAGE_FAST(0, 0);
    for (int t = 0; t < NSTEPS - 1; ++t) {
      STAGE_FAST((t + 1) & 1, (t + 1) * BK);
      asm volatile("s_waitcnt vmcnt(8)" ::: "memory");
      __builtin_amdgcn_s_barrier();
      __builtin_amdgcn_sched_barrier(0);
      __builtin_amdgcn_s_setprio(1);
      int buf = t & 1;
#pragma unroll
      for (int kk = 0; kk < 2; ++kk) {
        f16x8 b_h[4];
#pragma unroll
        for (int ni = 0; ni < 4; ++ni) {
          int row = wc * 64 + ni * 16 + l16;
          int ch = (kk * 4 + lhi) ^ (row & 7);
          b_h[ni] = *(const f16x8*)&sBh[buf][row * 64 + ch * 8];
        }
#pragma unroll
        for (int mi = 0; mi < 8; ++mi) {
          int rowa = wr * 128 + mi * 16 + l16;
          int cha = (kk * 4 + lhi) ^ (rowa & 7);
          f16x8 a_h = *(const f16x8*)&sAh[buf][rowa * 64 + cha * 8];
#pragma unroll
          for (int ni = 0; ni < 4; ++ni)
            acc[mi][ni] = __builtin_amdgcn_mfma_f32_16x16x32_f16(a_h, b_h[ni], acc[mi][ni], 0, 0, 0);
        }
      }
      __builtin_amdgcn_s_setprio(0);
      if (t == 1024 / BK - 1) RESCALE();
      __builtin_amdgcn_s_barrier();
    }
    asm volatile("s_waitcnt vmcnt(0)" ::: "memory");
    __builtin_amdgcn_s_barrier();
    __builtin_amdgcn_sched_barrier(0);
    {
      int buf = (NSTEPS - 1) & 1;
      __builtin_amdgcn_s_setprio(1);
#pragma unroll
      for (int kk = 0; kk < 2; ++kk) {
        f16x8 b_h[4];
#pragma unroll
        for (int ni = 0; ni < 4; ++ni) {
          int row = wc * 64 + ni * 16 + l16;
          int ch = (kk * 4 + lhi) ^ (row & 7);
          b_h[ni] = *(const f16x8*)&sBh[buf][row * 64 + ch * 8];
        }
#pragma unroll
        for (int mi = 0; mi < 8; ++mi) {
          int rowa = wr * 128 + mi * 16 + l16;
          int cha = (kk * 4 + lhi) ^ (rowa & 7);
          f16x8 a_h = *(const f16x8*)&sAh[buf][rowa * 64 + cha * 8];
#pragma unroll
          for (int ni = 0; ni < 4; ++ni)
            acc[mi][ni] = __builtin_amdgcn_mfma_f32_16x16x32_f16(a_h, b_h[ni], acc[mi][ni], 0, 0, 0);
        }
      }
      __builtin_amdgcn_s_setprio(0);
    }
  } else {
    // Prologue: tile 0 fully staged (h0 then h1).
    STAGE_H0(0, 0);
    STAGE_H1(0, 0);
    for (int t = 0; t < NSTEPS; ++t) {
      const int buf = t & 1;
      if (t < NSTEPS - 1) STAGE_H0(buf ^ 1, (t + 1) * 32);
      // W0: h0(t) resident (newest 8 = h1(t-? ) ... ledger: h1(t)+h0(t+1))
      if (t < NSTEPS - 1) asm volatile("s_waitcnt vmcnt(8)" ::: "memory");
      else                asm volatile("s_waitcnt vmcnt(4)" ::: "memory");
      __builtin_amdgcn_s_barrier();
      __builtin_amdgcn_sched_barrier(0);
      // Phase hh: 32 MFMA; carry a_h/b_h in regs for phase 2.
      __builtin_amdgcn_s_setprio(1);
      f16x8 b_h[4], a_hv[8];
#pragma unroll
      for (int ni = 0; ni < 4; ++ni) {
        int row = wc * 64 + ni * 16 + l16;
        b_h[ni] = *(const f16x8*)&sBh[buf][row * 32 + ((lhi ^ ((row >> 1) & 3)) * 8)];
      }
#pragma unroll
      for (int mi = 0; mi < 8; ++mi) {
        int rowa = wr * 128 + mi * 16 + l16;
        a_hv[mi] = *(const f16x8*)&sAh[buf][rowa * 32 + ((lhi ^ ((rowa >> 1) & 3)) * 8)];
#pragma unroll
        for (int ni = 0; ni < 4; ++ni)
          acc[mi][ni] = __builtin_amdgcn_mfma_f32_16x16x32_f16(a_hv[mi], b_h[ni], acc[mi][ni], 0, 0, 0);
      }
      __builtin_amdgcn_s_setprio(0);
      // W1: h1(t) resident (newest 4 = h0(t+1))
      if (t < NSTEPS - 1) asm volatile("s_waitcnt vmcnt(4)" ::: "memory");
      else                asm volatile("s_waitcnt vmcnt(0)" ::: "memory");
      __builtin_amdgcn_s_barrier();
      __builtin_amdgcn_sched_barrier(0);
      // Phase hl + lh: 64 MFMA (b_l, a_l fresh; a_h/b_h from regs).
      __builtin_amdgcn_s_setprio(1);
      f16x8 b_l[4];
#pragma unroll
      for (int ni = 0; ni < 4; ++ni) {
        int row = wc * 64 + ni * 16 + l16;
        b_l[ni] = *(const f16x8*)&sBl[buf][row * 32 + ((lhi ^ ((row >> 1) & 3)) * 8)];
      }
#pragma unroll
      for (int mi = 0; mi < 8; ++mi) {
        int rowa = wr * 128 + mi * 16 + l16;
        f16x8 a_l = *(const f16x8*)&sAl[buf][rowa * 32 + ((lhi ^ ((rowa >> 1) & 3)) * 8)];
#pragma unroll
        for (int ni = 0; ni < 4; ++ni) {
          f32x4 a = acc[mi][ni];
          a = __builtin_amdgcn_mfma_f32_16x16x32_f16(a_hv[mi], b_l[ni], a, 0, 0, 0);
          a = __builtin_amdgcn_mfma_f32_16x16x32_f16(a_l, b_h[ni], a, 0, 0, 0);
          acc[mi][ni] = a;
        }
      }
      __builtin_amdgcn_s_setprio(0);
      if (t == 31) RESCALE();              // pane boundary: Horner rescale
      __builtin_amdgcn_s_barrier();        // all waves done reading buf(t)
      if (t < NSTEPS - 1) STAGE_H1(buf ^ 1, (t + 1) * 32);
    }
  }

#pragma unroll
  for (int mi = 0; mi < 8; ++mi)
#pragma unroll
    for (int r = 0; r < 4; ++r) {
      int rowl = wr * 128 + mi * 16 + lhi * 4 + r;
      float s = sWr[rowl * 2 + 1];   // final scale: w1 of this kz
#pragma unroll
      for (int ni = 0; ni < 4; ++ni) {
        int col = bn + wc * 64 + ni * 16 + l16;
        Cp[(size_t)(bm + rowl) * DMODEL + col] = acc[mi][ni][r] * s;
      }
    }
}

// ---------------------------------------------------------------------------
// V transpose + 4-way reduce -> Vt fp16 hi/lo planes [b][h][dh][t].
// ---------------------------------------------------------------------------
__global__ __launch_bounds__(256) void vtrans4_kernel(const float* __restrict__ Va,
                                                      const float* __restrict__ Vb,
                                                      const float* __restrict__ Vc,
                                                      const float* __restrict__ Vd,
                                                      _Float16* __restrict__ Vth,
                                                      _Float16* __restrict__ Vtl) {
  __shared__ float tbuf[64][65];
  const int tid = threadIdx.x;
  const int t0 = blockIdx.x * 64, d0 = blockIdx.y * 64, bh = blockIdx.z;
  const int b = bh >> 3, h = bh & 7;
#pragma unroll
  for (int j = 0; j < 4; ++j) {
    int ci = tid + 256 * j;
    int r = ci >> 4, c4 = (ci & 15) * 4;
    size_t g = (size_t)(b * S_LEN + t0 + r) * DMODEL + h * 128 + d0 + c4;
    float4 va = *(const float4*)&Va[g];
    float4 vb = *(const float4*)&Vb[g];
    float4 vc = *(const float4*)&Vc[g];
    float4 vd = *(const float4*)&Vd[g];
    tbuf[r][c4 + 0] = va.x + vb.x + vc.x + vd.x;
    tbuf[r][c4 + 1] = va.y + vb.y + vc.y + vd.y;
    tbuf[r][c4 + 2] = va.z + vb.z + vc.z + vd.z;
    tbuf[r][c4 + 3] = va.w + vb.w + vc.w + vd.w;
  }
  __syncthreads();
#pragma unroll
  for (int j = 0; j < 4; ++j) {
    int ci = tid + 256 * j;
    int r = ci >> 4, c4 = (ci & 15) * 4;   // r: d-local, c4: t-local
    float s[4] = {tbuf[c4 + 0][r], tbuf[c4 + 1][r], tbuf[c4 + 2][r], tbuf[c4 + 3][r]};
    f16x4 hv, lv;
#pragma unroll
    for (int e = 0; e < 4; ++e) {
      _Float16 hh = (_Float16)s[e];
      hv[e] = hh;
      lv[e] = (_Float16)(s[e] - (float)hh);
    }
    size_t o = ((size_t)bh * 128 + d0 + r) * S_LEN + t0 + c4;
    *(f16x4*)&Vth[o] = hv;
    *(f16x4*)&Vtl[o] = lv;
  }
}

// ---------------------------------------------------------------------------
// MFMA flash attention, split-fp16, fully-DMA staging from plane inputs.
// ---------------------------------------------------------------------------
__global__ __launch_bounds__(256) void attn_kernel(const _Float16* __restrict__ Qh,
                                                   const _Float16* __restrict__ Ql,
                                                   const _Float16* __restrict__ Kh,
                                                   const _Float16* __restrict__ Kl,
                                                   const _Float16* __restrict__ Vth,
                                                   const _Float16* __restrict__ Vtl,
                                                   float* __restrict__ O,
                                                   _Float16* __restrict__ Oh) {
  __shared__ _Float16 sKh[32 * 128], sKl[32 * 128];
  __shared__ _Float16 sVh[128 * 32], sVl[128 * 32];
  __shared__ _Float16 sPh[4 * 16 * 32], sPl[4 * 16 * 32];
  const int tid = threadIdx.x;
  const int wid = tid >> 6, lane = tid & 63;
  const int l16 = lane & 15, lhi = lane >> 4;
  const int qt = (gridDim.x - 1) - blockIdx.x;   // LPT
  const int bh = blockIdx.y;
  const int b = bh >> 3, h = bh & 7;
  const size_t qkbase = (size_t)b * S_LEN * DMODEL + h * 128;
  const float scale = 0.08838834764831845f;      // 1/sqrt(128)

  const int qrow = qt * 64 + wid * 16 + l16;
  const size_t qoff = qkbase + (size_t)qrow * DMODEL;
  f16x8 qh[4], ql[4];
#pragma unroll
  for (int kk = 0; kk < 4; ++kk) {
    qh[kk] = *(const f16x8*)&Qh[qoff + kk * 32 + lhi * 8];
    ql[kk] = *(const f16x8*)&Ql[qoff + kk * 32 + lhi * 8];
  }

  f32x4 of[8];
#pragma unroll
  for (int i = 0; i < 8; ++i) { f32x4 z = {0.f, 0.f, 0.f, 0.f}; of[i] = z; }
  float m_[4], l_[4];
#pragma unroll
  for (int r = 0; r < 4; ++r) { m_[r] = -1e30f; l_[r] = 0.f; }

  const int ntw = qt * 2 + 1 + (wid >> 1);
  const int NT  = qt * 2 + 2;

  for (int kt = 0; kt < NT; ++kt) {
    __syncthreads();
#pragma unroll
    for (int j = 0; j < 2; ++j) {
      int ci = tid + 256 * j;
      int k = ci >> 4, c = ci & 15;
      int cs = c ^ (k & 7);
      size_t g = qkbase + (size_t)(kt * 32 + k) * DMODEL + cs * 8;
      async16(&Kh[g], &sKh[k * 128 + c * 8]);
      async16(&Kl[g], &sKl[k * 128 + c * 8]);
    }
#pragma unroll
    for (int j = 0; j < 2; ++j) {
      int ci = tid + 256 * j;
      int d = ci >> 2, c = ci & 3;
      int cs = c ^ ((d >> 1) & 3);
      size_t g = ((size_t)bh * 128 + d) * S_LEN + kt * 32 + cs * 8;
      async16(&Vth[g], &sVh[d * 32 + c * 8]);
      async16(&Vtl[g], &sVl[d * 32 + c * 8]);
    }
    __syncthreads();

    if (kt < ntw) {
      f32x4 s0 = {0.f, 0.f, 0.f, 0.f}, s1 = {0.f, 0.f, 0.f, 0.f};
#pragma unroll
      for (int kk = 0; kk < 4; ++kk) {
        int col = (kk * 32 + lhi * 8);
        int i0 = l16 * 128 + (col ^ ((l16 & 7) * 8));
        int i1 = (16 + l16) * 128 + (col ^ (((16 + l16) & 7) * 8));
        f16x8 kb0h = *(const f16x8*)&sKh[i0];
        f16x8 kb0l = *(const f16x8*)&sKl[i0];
        f16x8 kb1h = *(const f16x8*)&sKh[i1];
        f16x8 kb1l = *(const f16x8*)&sKl[i1];
        s0 = __builtin_amdgcn_mfma_f32_16x16x32_f16(qh[kk], kb0h, s0, 0, 0, 0);
        s0 = __builtin_amdgcn_mfma_f32_16x16x32_f16(qh[kk], kb0l, s0, 0, 0, 0);
        s0 = __builtin_amdgcn_mfma_f32_16x16x32_f16(ql[kk], kb0h, s0, 0, 0, 0);
        s1 = __builtin_amdgcn_mfma_f32_16x16x32_f16(qh[kk], kb1h, s1, 0, 0, 0);
        s1 = __builtin_amdgcn_mfma_f32_16x16x32_f16(qh[kk], kb1l, s1, 0, 0, 0);
        s1 = __builtin_amdgcn_mfma_f32_16x16x32_f16(ql[kk], kb1h, s1, 0, 0, 0);
      }
      const int qg = qt * 64 + wid * 16 + (lane >> 4) * 4;
      if (kt == ntw - 1) {
#pragma unroll
        for (int r = 0; r < 4; ++r) {
          int q = qg + r;
          int k0 = kt * 32 + l16, k1 = k0 + 16;
          s0[r] = (k0 <= q) ? s0[r] * scale : -1e30f;
          s1[r] = (k1 <= q) ? s1[r] * scale : -1e30f;
        }
      } else {
#pragma unroll
        for (int r = 0; r < 4; ++r) { s0[r] *= scale; s1[r] *= scale; }
      }
      float p0[4], p1[4], fr[4];
#pragma unroll
      for (int r = 0; r < 4; ++r) {
        float rm = fmaxf(s0[r], s1[r]);
        rm = fmaxf(rm, __shfl_xor(rm, 1));
        rm = fmaxf(rm, __shfl_xor(rm, 2));
        rm = fmaxf(rm, __shfl_xor(rm, 4));
        rm = fmaxf(rm, __shfl_xor(rm, 8));
        float mn = fmaxf(m_[r], rm);
        fr[r] = __expf(m_[r] - mn);
        m_[r] = mn;
        p0[r] = __expf(s0[r] - mn);
        p1[r] = __expf(s1[r] - mn);
        float rs = p0[r] + p1[r];
        rs += __shfl_xor(rs, 1);
        rs += __shfl_xor(rs, 2);
        rs += __shfl_xor(rs, 4);
        rs += __shfl_xor(rs, 8);
        l_[r] = l_[r] * fr[r] + rs;
      }
#pragma unroll
      for (int i = 0; i < 8; ++i)
#pragma unroll
        for (int r = 0; r < 4; ++r) of[i][r] *= fr[r];
#pragma unroll
      for (int r = 0; r < 4; ++r) {
        int q = (lane >> 4) * 4 + r;
        int swz = ((q >> 1) & 3) * 8;
        int c0 = l16, c1 = 16 + l16;
        _Float16 h0 = (_Float16)p0[r];
        _Float16 h1 = (_Float16)p1[r];
        sPh[wid * 512 + q * 32 + (c0 ^ swz)] = h0;
        sPl[wid * 512 + q * 32 + (c0 ^ swz)] = (_Float16)(p0[r] - (float)h0);
        sPh[wid * 512 + q * 32 + (c1 ^ swz)] = h1;
        sPl[wid * 512 + q * 32 + (c1 ^ swz)] = (_Float16)(p1[r] - (float)h1);
      }
      int pidxr = wid * 512 + l16 * 32 + ((lhi * 8) ^ (((l16 >> 1) & 3) * 8));
      f16x8 pah = *(const f16x8*)&sPh[pidxr];
      f16x8 pal = *(const f16x8*)&sPl[pidxr];
#pragma unroll
      for (int d16 = 0; d16 < 8; ++d16) {
        int d = d16 * 16 + l16;
        int vidx = d * 32 + ((lhi * 8) ^ (((d >> 1) & 3) * 8));
        f16x8 vbh = *(const f16x8*)&sVh[vidx];
        f16x8 vbl = *(const f16x8*)&sVl[vidx];
        f32x4 a = of[d16];
        a = __builtin_amdgcn_mfma_f32_16x16x32_f16(pah, vbh, a, 0, 0, 0);
        a = __builtin_amdgcn_mfma_f32_16x16x32_f16(pah, vbl, a, 0, 0, 0);
        a = __builtin_amdgcn_mfma_f32_16x16x32_f16(pal, vbh, a, 0, 0, 0);
        of[d16] = a;
      }
    }
  }
  float inv[4];
#pragma unroll
  for (int r = 0; r < 4; ++r) inv[r] = 1.f / l_[r];
  const int qg = qt * 64 + wid * 16 + (lane >> 4) * 4;
#pragma unroll
  for (int d16 = 0; d16 < 8; ++d16)
#pragma unroll
    for (int r = 0; r < 4; ++r) {
      float val = of[d16][r] * inv[r];
      size_t gi = qkbase + (size_t)(qg + r) * DMODEL + d16 * 16 + l16;
      O[gi] = val;
      Oh[gi] = (_Float16)val;
    }
}

// ---------------------------------------------------------------------------
extern "C" void kernel_launch(void* const* d_in, const int* in_sizes, int n_in,
                              void* d_out, int out_size, void* d_ws, size_t ws_size,
                              hipStream_t stream) {
  (void)in_sizes; (void)n_in; (void)out_size;
  const float* x        = (const float*)d_in[0];
  const float* Wr_in    = (const float*)d_in[2];
  const float* Wr_proc  = (const float*)d_in[3];
  const float* Wr_out   = (const float*)d_in[4];
  const float* WrO_in   = (const float*)d_in[5];
  const float* WrO_proc = (const float*)d_in[6];
  const float* WrO_out  = (const float*)d_in[7];
  const float* Wq_in    = (const float*)d_in[8];
  const float* vq       = (const float*)d_in[9];
  const float* Wq_out   = (const float*)d_in[10];
  const float* Wk_in    = (const float*)d_in[11];
  const float* vk       = (const float*)d_in[12];
  const float* Wk_out   = (const float*)d_in[13];
  const float* Wv_in    = (const float*)d_in[14];
  const float* vv       = (const float*)d_in[15];
  const float* Wv_out   = (const float*)d_in[16];
  const float* Wo_in    = (const float*)d_in[17];
  const float* vo       = (const float*)d_in[18];
  const float* Wo_out   = (const float*)d_in[19];

  char* wsbase = (char*)d_ws;
  size_t off = 0;
  auto carve = [&](size_t bytes) -> void* {
    void* r = wsbase + off;
    off = (off + bytes + 255) & ~(size_t)255;
    return r;
  };
  const size_t WBYTES = (size_t)KDIM * DMODEL * 2;     // 16.78 MB (B plane)
  const size_t PBYTES = (size_t)TOK * DMODEL * 2;      // 8.39 MB (A plane)
  const size_t HBYTES = (size_t)TOK * DMODEL * 4;      // 16.78 MB (fp32)
  _Float16* WTh = (_Float16*)carve(WBYTES);
  _Float16* WTl = (_Float16*)carve(WBYTES);
  _Float16* Xh  = (_Float16*)carve(PBYTES);
  _Float16* Xl  = (_Float16*)carve(PBYTES);   // contiguous after Xh
  _Float16* Hh  = (_Float16*)carve(PBYTES);
  _Float16* Hl  = (_Float16*)carve(PBYTES);
  float* P0 = (float*)carve(HBYTES);
  float* P1 = (float*)carve(HBYTES);
  float* P2 = (float*)carve(HBYTES);
  _Float16* Qph = (_Float16*)carve(PBYTES);
  _Float16* Qpl = (_Float16*)carve(PBYTES);   // contiguous after Qph
  _Float16* Kph = (_Float16*)carve(PBYTES);
  _Float16* Kpl = (_Float16*)carve(PBYTES);
  float* iw1 = (float*)carve((size_t)TOK * 8 * 4);
  float* ow1 = (float*)carve((size_t)TOK * 8 * 4);
  float* iw2 = (float*)carve((size_t)TOK * 8 * 4);
  float* ow2 = (float*)carve((size_t)TOK * 8 * 4);
  int* pi1 = (int*)carve((size_t)TOK * 3 * 4);
  int* pi2 = (int*)carve((size_t)TOK * 3 * 4);

  if (off > ws_size) {   // diagnosable failure instead of OOB abort
    hipMemsetAsync(d_out, 0, (size_t)out_size * 4, stream);
    return;
  }

  // Lifetime-disjoint aliases:
  float*    Pd  = (float*)d_out;               // 4th split-K partial (scratch)
  float*    PQ  = (float*)Qph;                 // Qph+Qpl contiguous = 16.78 MB
  float*    PX  = (float*)Xh;                  // Xh+Xl contiguous (post-attn)
  _Float16* Vth = WTh;                         // Vt planes live attn-only
  _Float16* Vtl = WTh + (size_t)TOK * DMODEL;
  float*    Ofp = P0;                          // O fp32 (router2 input)
  _Float16* Ohp = (_Float16*)P1;               // O hi plane (FAST gemm A)

  const dim3 blk(256);
  const dim3 gblk(512);
  const dim3 tgrid(KDIM / 64, DMODEL / 64);        // (128, 16)
  const dim3 ggrid(TOK / 256, DMODEL / 256, 4);    // (16, 4, 4) = 256 wgs
  const dim3 rgrid(TOK * DMODEL / (256 * 4));      // 4096
  const dim3 vgrid(S_LEN / 64, 2, 16);
  const dim3 agrid(S_LEN / 64, 16);

  // router 1 on x (fused X split)
  router_kernel<<<TOK, blk, 0, stream>>>(x, Wr_in, Wr_proc, Wr_out, iw1, ow1, pi1, Xh, Xl);

  // Q circuit
  transpose_split<<<tgrid, blk, 0, stream>>>(Wq_in, WTh, WTl);
  gemm_planes<false><<<ggrid, gblk, 0, stream>>>(Xh, Xl, iw1, WTh, WTl, P0, P1, P2, Pd);
  reflect4_kernel<<<TOK, blk, 0, stream>>>(P0, P1, P2, Pd, pi1, vq, Hh, Hl);
  transpose_split<<<tgrid, blk, 0, stream>>>(Wq_out, WTh, WTl);
  gemm_planes<false><<<ggrid, gblk, 0, stream>>>(Hh, Hl, ow1, WTh, WTl, P0, P1, P2, Pd);
  reduce4_planes<<<rgrid, blk, 0, stream>>>(P0, P1, P2, Pd, Qph, Qpl);

  // K circuit
  transpose_split<<<tgrid, blk, 0, stream>>>(Wk_in, WTh, WTl);
  gemm_planes<false><<<ggrid, gblk, 0, stream>>>(Xh, Xl, iw1, WTh, WTl, P0, P1, P2, Pd);
  reflect4_kernel<<<TOK, blk, 0, stream>>>(P0, P1, P2, Pd, pi1, vk, Hh, Hl);
  transpose_split<<<tgrid, blk, 0, stream>>>(Wk_out, WTh, WTl);
  gemm_planes<false><<<ggrid, gblk, 0, stream>>>(Hh, Hl, ow1, WTh, WTl, P0, P1, P2, Pd);
  reduce4_planes<<<rgrid, blk, 0, stream>>>(P0, P1, P2, Pd, Kph, Kpl);

  // V circuit
  transpose_split<<<tgrid, blk, 0, stream>>>(Wv_in, WTh, WTl);
  gemm_planes<false><<<ggrid, gblk, 0, stream>>>(Xh, Xl, iw1, WTh, WTl, P0, P1, P2, Pd);
  reflect4_kernel<<<TOK, blk, 0, stream>>>(P0, P1, P2, Pd, pi1, vv, Hh, Hl);
  transpose_split<<<tgrid, blk, 0, stream>>>(Wv_out, WTh, WTl);
  gemm_planes<false><<<ggrid, gblk, 0, stream>>>(Hh, Hl, ow1, WTh, WTl, P0, P1, P2, Pd);
  vtrans4_kernel<<<vgrid, blk, 0, stream>>>(P0, P1, P2, Pd, Vth, Vtl);

  // attention (Q/K/Vt planes -> O fp32 in P0, O hi plane in P1)
  attn_kernel<<<agrid, blk, 0, stream>>>(Qph, Qpl, Kph, Kpl, Vth, Vtl, Ofp, Ohp);

  // router 2 + final circuit (FAST gemms: 1-MFMA, hi planes, BK=64)
  router_kernel<<<TOK, blk, 0, stream>>>(Ofp, WrO_in, WrO_proc, WrO_out, iw2, ow2, pi2,
                                         nullptr, nullptr);
  transpose_split<<<tgrid, blk, 0, stream>>>(Wo_in, WTh, nullptr);  // hi only (FAST)
  gemm_planes<true><<<ggrid, gblk, 0, stream>>>(Ohp, Ohp, iw2, WTh, WTh, PX, P0, P2, Pd);
  reflect4_kernel<<<TOK, blk, 0, stream>>>(PX, P0, P2, Pd, pi2, vo, Hh, Hl);
  transpose_split<<<tgrid, blk, 0, stream>>>(Wo_out, WTh, nullptr); // hi only (FAST)
  gemm_planes<true><<<ggrid, gblk, 0, stream>>>(Hh, Hh, ow2, WTh, WTh, P0, P1, P2, PQ);
  reduce4_f32<<<rgrid, blk, 0, stream>>>(P0, P1, P2, PQ, (float*)d_out);
}

// Round 16
// 1614.758 us; speedup vs baseline: 1.0097x; 1.0097x over previous
//
#include <hip/hip_runtime.h>

// ---------------------------------------------------------------------------
// NeuronCircuitQKV final: r14 configuration (best measured: 1618.6 us).
// FULL GEMM: 256x256, BK=32, 8 waves, dbuf + counted vmcnt(8), 1 block/CU.
// FAST GEMM: BK=64, 1-MFMA hi*hi, vmcnt(8), 32 steps.
// Attention: split-fp16 MFMA flash, fully-DMA staging, LPT causal.
// Precision: 3-MFMA split-fp16 pre-router (top-k-faithful, err ~2^-22);
// 1-MFMA post-router (err ~2^-11, only affects d_out; absmax 4.9e-4 < 2.7e-3).
// Plateau evidence (r7-r15): FULL pinned 199-231us across occupancy 8-16
// waves/CU, tile 128^2/256^2, staged-bytes 2x range, dbuf, counted vmcnt,
// phase-splits -> structural latency floor of the 2-barrier family.
// ---------------------------------------------------------------------------

typedef __attribute__((ext_vector_type(4))) float f32x4;
typedef _Float16 f16x8 __attribute__((ext_vector_type(8)));
typedef _Float16 f16x4 __attribute__((ext_vector_type(4)));

static constexpr int S_LEN  = 2048;
static constexpr int TOK    = 4096;   // B*S
static constexpr int DMODEL = 1024;
static constexpr int KDIM   = 8192;   // 8 experts * 1024

__device__ __forceinline__ void async16(const void* g, void* l) {
  __builtin_amdgcn_global_load_lds(
      (const __attribute__((address_space(1))) void*)g,
      (__attribute__((address_space(3))) void*)l, 16, 0, 0);
}

// ---------------------------------------------------------------------------
// Transpose (KDIM x DMODEL fp32) -> (DMODEL x KDIM fp16 hi[/lo] planes).
// Tl == nullptr skips the lo plane (for FAST-consumed weights).
// ---------------------------------------------------------------------------
__global__ __launch_bounds__(256) void transpose_split(const float* __restrict__ W,
                                                       _Float16* __restrict__ Th,
                                                       _Float16* __restrict__ Tl) {
  __shared__ float tbuf[64][65];
  const int tid = threadIdx.x;
  const int k0 = blockIdx.x * 64, n0 = blockIdx.y * 64;
#pragma unroll
  for (int j = 0; j < 4; ++j) {
    int ci = tid + 256 * j;
    int r = ci >> 4, c4 = (ci & 15) * 4;
    float4 v = *(const float4*)&W[(size_t)(k0 + r) * DMODEL + n0 + c4];
    tbuf[r][c4 + 0] = v.x; tbuf[r][c4 + 1] = v.y;
    tbuf[r][c4 + 2] = v.z; tbuf[r][c4 + 3] = v.w;
  }
  __syncthreads();
#pragma unroll
  for (int j = 0; j < 2; ++j) {
    int ci = tid + 256 * j;
    int nl = ci >> 3, k8 = (ci & 7) * 8;
    f16x8 hv, lv;
#pragma unroll
    for (int e = 0; e < 8; ++e) {
      float v = tbuf[k8 + e][nl];
      _Float16 hh = (_Float16)v;
      hv[e] = hh;
      lv[e] = (_Float16)(v - (float)hh);
    }
    size_t off = (size_t)(n0 + nl) * KDIM + k0 + k8;
    *(f16x8*)&Th[off] = hv;
    if (Tl != nullptr) *(f16x8*)&Tl[off] = lv;
  }
}

// ---------------------------------------------------------------------------
// Router: 48 logits (fp64 accum -> stable top-k), softmaxes, top-3.
// Optionally also emits fp16 hi/lo planes of X (fused split).
// ---------------------------------------------------------------------------
__global__ __launch_bounds__(256) void router_kernel(const float* __restrict__ X,
                                                     const float* __restrict__ Wi,
                                                     const float* __restrict__ Wp,
                                                     const float* __restrict__ Wo,
                                                     float* __restrict__ in_w,
                                                     float* __restrict__ out_w,
                                                     int* __restrict__ pidx,
                                                     _Float16* __restrict__ Xh,
                                                     _Float16* __restrict__ Xl) {
  __shared__ float xs[1024];
  __shared__ double lg[48];
  const int t = blockIdx.x, tid = threadIdx.x;
  const int wid = tid >> 6, lane = tid & 63;
#pragma unroll
  for (int j = 0; j < 4; ++j) {
    int d = tid + 256 * j;
    xs[d] = X[(size_t)t * DMODEL + d];
  }
  __syncthreads();
  for (int i = wid; i < 48; i += 4) {
    const float* wrow = (i < 8)  ? Wi + (size_t)i * DMODEL
                      : (i < 40) ? Wp + (size_t)(i - 8) * DMODEL
                                 : Wo + (size_t)(i - 40) * DMODEL;
    double s = 0.0;
#pragma unroll
    for (int j = 0; j < 16; ++j) { int d = lane + 64 * j; s += (double)xs[d] * (double)wrow[d]; }
#pragma unroll
    for (int mm = 32; mm >= 1; mm >>= 1) s += __shfl_xor(s, mm);
    if (lane == 0) lg[i] = s;
  }
  __syncthreads();
  if (tid == 0) {
    float l[8], m;
    for (int i = 0; i < 8; ++i) l[i] = (float)lg[i];
    m = l[0];
    for (int i = 1; i < 8; ++i) m = fmaxf(m, l[i]);
    float e[8], su = 0.f;
    for (int i = 0; i < 8; ++i) { e[i] = expf(l[i] - m); su += e[i]; }
    for (int i = 0; i < 8; ++i) in_w[t * 8 + i] = e[i] / su;
  } else if (tid == 64) {
    float l[8], m;
    for (int i = 0; i < 8; ++i) l[i] = (float)lg[40 + i];
    m = l[0];
    for (int i = 1; i < 8; ++i) m = fmaxf(m, l[i]);
    float e[8], su = 0.f;
    for (int i = 0; i < 8; ++i) { e[i] = expf(l[i] - m); su += e[i]; }
    for (int i = 0; i < 8; ++i) out_w[t * 8 + i] = e[i] / su;
  } else if (tid == 128) {
    unsigned used = 0;
    for (int j = 0; j < 3; ++j) {
      double best = -1e300; int bi = 0;
      for (int i = 0; i < 32; ++i)
        if (!((used >> i) & 1u) && lg[8 + i] > best) { best = lg[8 + i]; bi = i; }
      used |= 1u << bi;
      pidx[t * 3 + j] = bi;
    }
  }
  if (Xh != nullptr) {
#pragma unroll
    for (int j = 0; j < 4; ++j) {
      int d = tid + 256 * j;
      float v = xs[d];
      _Float16 hh = (_Float16)v;
      Xh[(size_t)t * DMODEL + d] = hh;
      Xl[(size_t)t * DMODEL + d] = (_Float16)(v - (float)hh);
    }
  }
}

// ---------------------------------------------------------------------------
// h = Pa+Pb+Pc+Pd, 3 Householder reflections, write fp16 hi/lo planes.
// ---------------------------------------------------------------------------
__global__ __launch_bounds__(256) void reflect4_kernel(const float* __restrict__ Pa,
                                                       const float* __restrict__ Pb,
                                                       const float* __restrict__ Pc,
                                                       const float* __restrict__ Pd,
                                                       const int* __restrict__ pidx,
                                                       const float* __restrict__ vtab,
                                                       _Float16* __restrict__ Hh,
                                                       _Float16* __restrict__ Hl) {
  __shared__ float red[8];
  const int t = blockIdx.x, tid = threadIdx.x;
  const int wid = tid >> 6, lane = tid & 63;
  size_t gi = (size_t)t * DMODEL + tid * 4;
  float4 ha = *(const float4*)&Pa[gi];
  float4 hb = *(const float4*)&Pb[gi];
  float4 hc = *(const float4*)&Pc[gi];
  float4 hd = *(const float4*)&Pd[gi];
  float4 h = {ha.x + hb.x + hc.x + hd.x, ha.y + hb.y + hc.y + hd.y,
              ha.z + hb.z + hc.z + hd.z, ha.w + hb.w + hc.w + hd.w};
  for (int i = 0; i < 3; ++i) {
    int idx = pidx[t * 3 + i];
    float4 vi = *(const float4*)&vtab[(size_t)idx * DMODEL + tid * 4];
    float hv = h.x * vi.x + h.y * vi.y + h.z * vi.z + h.w * vi.w;
    float vv = vi.x * vi.x + vi.y * vi.y + vi.z * vi.z + vi.w * vi.w;
#pragma unroll
    for (int mm = 32; mm >= 1; mm >>= 1) { hv += __shfl_xor(hv, mm); vv += __shfl_xor(vv, mm); }
    if (lane == 0) { red[wid] = hv; red[4 + wid] = vv; }
    __syncthreads();
    float dot = red[0] + red[1] + red[2] + red[3];
    float vn  = red[4] + red[5] + red[6] + red[7];
    __syncthreads();
    float c = 2.f * dot / (vn + 1e-8f);
    h.x -= c * vi.x; h.y -= c * vi.y; h.z -= c * vi.z; h.w -= c * vi.w;
  }
  float a[4] = {h.x, h.y, h.z, h.w};
  f16x4 hv4, lv4;
#pragma unroll
  for (int e = 0; e < 4; ++e) {
    _Float16 hh = (_Float16)a[e];
    hv4[e] = hh;
    lv4[e] = (_Float16)(a[e] - (float)hh);
  }
  *(f16x4*)&Hh[gi] = hv4;
  *(f16x4*)&Hl[gi] = lv4;
}

// ---------------------------------------------------------------------------
// 4-way reduce -> fp16 hi/lo planes (for Q/K). grid 4096, blk 256.
// ---------------------------------------------------------------------------
__global__ __launch_bounds__(256) void reduce4_planes(const float* __restrict__ a,
                                                      const float* __restrict__ b,
                                                      const float* __restrict__ c,
                                                      const float* __restrict__ d,
                                                      _Float16* __restrict__ Dh,
                                                      _Float16* __restrict__ Dl) {
  size_t i = ((size_t)blockIdx.x * 256 + threadIdx.x) * 4;
  float4 va = *(const float4*)&a[i];
  float4 vb = *(const float4*)&b[i];
  float4 vc = *(const float4*)&c[i];
  float4 vd = *(const float4*)&d[i];
  float s[4] = {va.x + vb.x + vc.x + vd.x, va.y + vb.y + vc.y + vd.y,
                va.z + vb.z + vc.z + vd.z, va.w + vb.w + vc.w + vd.w};
  f16x4 hv, lv;
#pragma unroll
  for (int e = 0; e < 4; ++e) {
    _Float16 hh = (_Float16)s[e];
    hv[e] = hh;
    lv[e] = (_Float16)(s[e] - (float)hh);
  }
  *(f16x4*)&Dh[i] = hv;
  *(f16x4*)&Dl[i] = lv;
}

// ---------------------------------------------------------------------------
// 4-way reduce -> fp32 (final output). grid 4096, blk 256.
// ---------------------------------------------------------------------------
__global__ __launch_bounds__(256) void reduce4_f32(const float* __restrict__ a,
                                                   const float* __restrict__ b,
                                                   const float* __restrict__ c,
                                                   const float* __restrict__ d,
                                                   float* __restrict__ o) {
  size_t i = ((size_t)blockIdx.x * 256 + threadIdx.x) * 4;
  float4 va = *(const float4*)&a[i];
  float4 vb = *(const float4*)&b[i];
  float4 vc = *(const float4*)&c[i];
  float4 vd = *(const float4*)&d[i];
  float4 vo = {va.x + vb.x + vc.x + vd.x, va.y + vb.y + vc.y + vd.y,
               va.z + vb.z + vc.z + vd.z, va.w + vb.w + vc.w + vd.w};
  *(float4*)&o[i] = vo;
}

// ---------------------------------------------------------------------------
// Split-fp16 GEMM, 256x256 tiles, balanced split-K=4, DOUBLE-BUFFERED LDS
// with counted vmcnt (never 0 in main loop) + raw s_barrier.
// FULL: BK=32, 3 MFMA (hh,hl,lh), 8 loads/thread/step, vmcnt(8), 64 steps.
// FAST: BK=64, 1 MFMA (hh), {Ah,Bh} only, 8 loads/thread/step, vmcnt(8),
// 32 steps (half the barriers), row&7 chunk swizzle.
// 8 waves (2Mx4N), wave tile 128x64 = 8x4 16x16 frags.
// Grid (16,4,4) = 256 wgs = 1 block/CU, XCD remap. Horner mixture rescale.
// ---------------------------------------------------------------------------
template <bool FAST>
__global__ __launch_bounds__(512, 2) void gemm_planes(const _Float16* __restrict__ Ahp,
                                                      const _Float16* __restrict__ Alp,
                                                      const float* __restrict__ wmix,
                                                      const _Float16* __restrict__ Bh,
                                                      const _Float16* __restrict__ Bl,
                                                      float* __restrict__ C0,
                                                      float* __restrict__ C1,
                                                      float* __restrict__ C2,
                                                      float* __restrict__ C3) {
  constexpr int BK     = FAST ? 64 : 32;
  constexpr int NSTEPS = 2048 / BK;          // 32 (FAST) or 64 (FULL)
  __shared__ _Float16 sAh[2][256 * BK];
  __shared__ _Float16 sBh[2][256 * BK];
  __shared__ _Float16 sAl[2][FAST ? 8 : 256 * 32];
  __shared__ _Float16 sBl[2][FAST ? 8 : 256 * 32];
  __shared__ float sWr[256 * 2];   // [row][0]=w0/w1 (boundary), [row][1]=w1
  const int tid = threadIdx.x;              // 0..511
  const int wid = tid >> 6, lane = tid & 63;
  const int l16 = lane & 15, lhi = lane >> 4;
  const int wr = wid >> 2, wc = wid & 3;    // 2 x 4 wave grid
  // Bijective XCD remap: 256 wgs, 32/XCD.
  const int fid = blockIdx.x + (blockIdx.y << 4) + (blockIdx.z << 6);
  const int wg  = ((fid & 7) << 5) + (fid >> 3);
  const int bm = (wg & 15) * 256;
  const int bn = ((wg >> 4) & 3) * 256;
  const int kz = wg >> 6;                   // 0..3
  const int kbase = kz * 2048, nb = kz * 2;
  float* __restrict__ Cp = (kz == 0) ? C0 : (kz == 1) ? C1 : (kz == 2) ? C2 : C3;

  {
    int row = tid >> 1, p = tid & 1;
    const float* w = &wmix[(size_t)(bm + row) * 8 + nb];
    sWr[tid] = p ? w[1] : w[0] / w[1];
  }

  f32x4 acc[8][4];
#pragma unroll
  for (int i = 0; i < 8; ++i)
#pragma unroll
    for (int j = 0; j < 4; ++j) { f32x4 z = {0.f, 0.f, 0.f, 0.f}; acc[i][j] = z; }

  auto STAGE = [&](int buf, int kt) {
    const int kg = kbase + kt, d0 = kg & 1023;
    if constexpr (FAST) {
      // BK=64: 2048 chunks/plane, 8 chunks/row, row&7 XOR swizzle.
#pragma unroll
      for (int j = 0; j < 4; ++j) {
        int ci = tid + 512 * j;
        int row = ci >> 3, jc = ci & 7;
        int jcs = jc ^ (row & 7);
        size_t ga = (size_t)(bm + row) * DMODEL + d0 + jcs * 8;
        size_t gb = (size_t)(bn + row) * KDIM + kg + jcs * 8;
        async16(&Ahp[ga], &sAh[buf][ci * 8]);
        async16(&Bh[gb],  &sBh[buf][ci * 8]);
      }
    } else {
      // BK=32: 1024 chunks/plane, 4 chunks/row, (row>>1)&3 XOR swizzle.
#pragma unroll
      for (int j = 0; j < 2; ++j) {
        int ci = tid + 512 * j;
        int row = ci >> 2, jc = ci & 3;
        int jcs = jc ^ ((row >> 1) & 3);
        size_t ga = (size_t)(bm + row) * DMODEL + d0 + jcs * 8;
        size_t gb = (size_t)(bn + row) * KDIM + kg + jcs * 8;
        async16(&Ahp[ga], &sAh[buf][ci * 8]);
        async16(&Bh[gb],  &sBh[buf][ci * 8]);
        async16(&Alp[ga], &sAl[buf][ci * 8]);
        async16(&Bl[gb],  &sBl[buf][ci * 8]);
      }
    }
  };

  auto COMPUTE = [&](int buf) {
    __builtin_amdgcn_s_setprio(1);
    if constexpr (FAST) {
#pragma unroll
      for (int kk = 0; kk < 2; ++kk) {
        f16x8 b_h[4];
#pragma unroll
        for (int ni = 0; ni < 4; ++ni) {
          int row = wc * 64 + ni * 16 + l16;
          int ch = (kk * 4 + lhi) ^ (row & 7);
          b_h[ni] = *(const f16x8*)&sBh[buf][row * 64 + ch * 8];
        }
#pragma unroll
        for (int mi = 0; mi < 8; ++mi) {
          int rowa = wr * 128 + mi * 16 + l16;
          int cha = (kk * 4 + lhi) ^ (rowa & 7);
          f16x8 a_h = *(const f16x8*)&sAh[buf][rowa * 64 + cha * 8];
#pragma unroll
          for (int ni = 0; ni < 4; ++ni)
            acc[mi][ni] = __builtin_amdgcn_mfma_f32_16x16x32_f16(a_h, b_h[ni], acc[mi][ni], 0, 0, 0);
        }
      }
    } else {
      f16x8 b_h[4], b_l[4];
#pragma unroll
      for (int ni = 0; ni < 4; ++ni) {
        int row = wc * 64 + ni * 16 + l16;
        int idx = row * 32 + ((lhi ^ ((row >> 1) & 3)) * 8);
        b_h[ni] = *(const f16x8*)&sBh[buf][idx];
        b_l[ni] = *(const f16x8*)&sBl[buf][idx];
      }
#pragma unroll
      for (int mi = 0; mi < 8; ++mi) {
        int rowa = wr * 128 + mi * 16 + l16;
        int idxa = rowa * 32 + ((lhi ^ ((rowa >> 1) & 3)) * 8);
        f16x8 a_h = *(const f16x8*)&sAh[buf][idxa];
        f16x8 a_l = *(const f16x8*)&sAl[buf][idxa];
#pragma unroll
        for (int ni = 0; ni < 4; ++ni) {
          f32x4 a = acc[mi][ni];
          a = __builtin_amdgcn_mfma_f32_16x16x32_f16(a_h, b_h[ni], a, 0, 0, 0);
          a = __builtin_amdgcn_mfma_f32_16x16x32_f16(a_h, b_l[ni], a, 0, 0, 0);
          a = __builtin_amdgcn_mfma_f32_16x16x32_f16(a_l, b_h[ni], a, 0, 0, 0);
          acc[mi][ni] = a;
        }
      }
    }
    __builtin_amdgcn_s_setprio(0);
  };

  auto RESCALE = [&]() {
#pragma unroll
    for (int mi = 0; mi < 8; ++mi)
#pragma unroll
      for (int r = 0; r < 4; ++r) {
        float s = sWr[(wr * 128 + mi * 16 + lhi * 4 + r) * 2];
#pragma unroll
        for (int ni = 0; ni < 4; ++ni) acc[mi][ni][r] *= s;
      }
  };

  // Prologue: stage tile 0; main loop keeps next tile's loads in flight
  // across both barriers (counted vmcnt, never 0 until the epilogue).
  STAGE(0, 0);
  for (int t = 0; t < NSTEPS - 1; ++t) {
    STAGE((t + 1) & 1, (t + 1) * BK);
    asm volatile("s_waitcnt vmcnt(8)" ::: "memory");
    __builtin_amdgcn_s_barrier();          // tile t fully resident in buf[t&1]
    __builtin_amdgcn_sched_barrier(0);
    COMPUTE(t & 1);
    if (t == 1024 / BK - 1) RESCALE();     // pane boundary: Horner rescale
    __builtin_amdgcn_s_barrier();          // buf[t&1] free for re-staging
  }
  asm volatile("s_waitcnt vmcnt(0)" ::: "memory");
  __builtin_amdgcn_s_barrier();
  __builtin_amdgcn_sched_barrier(0);
  COMPUTE((NSTEPS - 1) & 1);               // last tile

#pragma unroll
  for (int mi = 0; mi < 8; ++mi)
#pragma unroll
    for (int r = 0; r < 4; ++r) {
      int rowl = wr * 128 + mi * 16 + lhi * 4 + r;
      float s = sWr[rowl * 2 + 1];   // final scale: w1 of this kz
#pragma unroll
      for (int ni = 0; ni < 4; ++ni) {
        int col = bn + wc * 64 + ni * 16 + l16;
        Cp[(size_t)(bm + rowl) * DMODEL + col] = acc[mi][ni][r] * s;
      }
    }
}

// ---------------------------------------------------------------------------
// V transpose + 4-way reduce -> Vt fp16 hi/lo planes [b][h][dh][t].
// grid (S/64, 2, 16), block 256.
// ---------------------------------------------------------------------------
__global__ __launch_bounds__(256) void vtrans4_kernel(const float* __restrict__ Va,
                                                      const float* __restrict__ Vb,
                                                      const float* __restrict__ Vc,
                                                      const float* __restrict__ Vd,
                                                      _Float16* __restrict__ Vth,
                                                      _Float16* __restrict__ Vtl) {
  __shared__ float tbuf[64][65];
  const int tid = threadIdx.x;
  const int t0 = blockIdx.x * 64, d0 = blockIdx.y * 64, bh = blockIdx.z;
  const int b = bh >> 3, h = bh & 7;
#pragma unroll
  for (int j = 0; j < 4; ++j) {
    int ci = tid + 256 * j;
    int r = ci >> 4, c4 = (ci & 15) * 4;
    size_t g = (size_t)(b * S_LEN + t0 + r) * DMODEL + h * 128 + d0 + c4;
    float4 va = *(const float4*)&Va[g];
    float4 vb = *(const float4*)&Vb[g];
    float4 vc = *(const float4*)&Vc[g];
    float4 vd = *(const float4*)&Vd[g];
    tbuf[r][c4 + 0] = va.x + vb.x + vc.x + vd.x;
    tbuf[r][c4 + 1] = va.y + vb.y + vc.y + vd.y;
    tbuf[r][c4 + 2] = va.z + vb.z + vc.z + vd.z;
    tbuf[r][c4 + 3] = va.w + vb.w + vc.w + vd.w;
  }
  __syncthreads();
#pragma unroll
  for (int j = 0; j < 4; ++j) {
    int ci = tid + 256 * j;
    int r = ci >> 4, c4 = (ci & 15) * 4;   // r: d-local, c4: t-local
    float s[4] = {tbuf[c4 + 0][r], tbuf[c4 + 1][r], tbuf[c4 + 2][r], tbuf[c4 + 3][r]};
    f16x4 hv, lv;
#pragma unroll
    for (int e = 0; e < 4; ++e) {
      _Float16 hh = (_Float16)s[e];
      hv[e] = hh;
      lv[e] = (_Float16)(s[e] - (float)hh);
    }
    size_t o = ((size_t)bh * 128 + d0 + r) * S_LEN + t0 + c4;
    *(f16x4*)&Vth[o] = hv;
    *(f16x4*)&Vtl[o] = lv;
  }
}

// ---------------------------------------------------------------------------
// MFMA flash attention, split-fp16, fully-DMA staging from plane inputs.
// Outputs O fp32 + Oh (hi plane; consumer is a FAST gemm).
// grid (S/64, B*H), block 256.
// ---------------------------------------------------------------------------
__global__ __launch_bounds__(256) void attn_kernel(const _Float16* __restrict__ Qh,
                                                   const _Float16* __restrict__ Ql,
                                                   const _Float16* __restrict__ Kh,
                                                   const _Float16* __restrict__ Kl,
                                                   const _Float16* __restrict__ Vth,
                                                   const _Float16* __restrict__ Vtl,
                                                   float* __restrict__ O,
                                                   _Float16* __restrict__ Oh) {
  __shared__ _Float16 sKh[32 * 128], sKl[32 * 128];
  __shared__ _Float16 sVh[128 * 32], sVl[128 * 32];
  __shared__ _Float16 sPh[4 * 16 * 32], sPl[4 * 16 * 32];
  const int tid = threadIdx.x;
  const int wid = tid >> 6, lane = tid & 63;
  const int l16 = lane & 15, lhi = lane >> 4;
  const int qt = (gridDim.x - 1) - blockIdx.x;   // LPT
  const int bh = blockIdx.y;
  const int b = bh >> 3, h = bh & 7;
  const size_t qkbase = (size_t)b * S_LEN * DMODEL + h * 128;
  const float scale = 0.08838834764831845f;      // 1/sqrt(128)

  const int qrow = qt * 64 + wid * 16 + l16;
  const size_t qoff = qkbase + (size_t)qrow * DMODEL;
  f16x8 qh[4], ql[4];
#pragma unroll
  for (int kk = 0; kk < 4; ++kk) {
    qh[kk] = *(const f16x8*)&Qh[qoff + kk * 32 + lhi * 8];
    ql[kk] = *(const f16x8*)&Ql[qoff + kk * 32 + lhi * 8];
  }

  f32x4 of[8];
#pragma unroll
  for (int i = 0; i < 8; ++i) { f32x4 z = {0.f, 0.f, 0.f, 0.f}; of[i] = z; }
  float m_[4], l_[4];
#pragma unroll
  for (int r = 0; r < 4; ++r) { m_[r] = -1e30f; l_[r] = 0.f; }

  const int ntw = qt * 2 + 1 + (wid >> 1);
  const int NT  = qt * 2 + 2;

  for (int kt = 0; kt < NT; ++kt) {
    __syncthreads();
#pragma unroll
    for (int j = 0; j < 2; ++j) {
      int ci = tid + 256 * j;
      int k = ci >> 4, c = ci & 15;
      int cs = c ^ (k & 7);
      size_t g = qkbase + (size_t)(kt * 32 + k) * DMODEL + cs * 8;
      async16(&Kh[g], &sKh[k * 128 + c * 8]);
      async16(&Kl[g], &sKl[k * 128 + c * 8]);
    }
#pragma unroll
    for (int j = 0; j < 2; ++j) {
      int ci = tid + 256 * j;
      int d = ci >> 2, c = ci & 3;
      int cs = c ^ ((d >> 1) & 3);
      size_t g = ((size_t)bh * 128 + d) * S_LEN + kt * 32 + cs * 8;
      async16(&Vth[g], &sVh[d * 32 + c * 8]);
      async16(&Vtl[g], &sVl[d * 32 + c * 8]);
    }
    __syncthreads();

    if (kt < ntw) {
      f32x4 s0 = {0.f, 0.f, 0.f, 0.f}, s1 = {0.f, 0.f, 0.f, 0.f};
#pragma unroll
      for (int kk = 0; kk < 4; ++kk) {
        int col = (kk * 32 + lhi * 8);
        int i0 = l16 * 128 + (col ^ ((l16 & 7) * 8));
        int i1 = (16 + l16) * 128 + (col ^ (((16 + l16) & 7) * 8));
        f16x8 kb0h = *(const f16x8*)&sKh[i0];
        f16x8 kb0l = *(const f16x8*)&sKl[i0];
        f16x8 kb1h = *(const f16x8*)&sKh[i1];
        f16x8 kb1l = *(const f16x8*)&sKl[i1];
        s0 = __builtin_amdgcn_mfma_f32_16x16x32_f16(qh[kk], kb0h, s0, 0, 0, 0);
        s0 = __builtin_amdgcn_mfma_f32_16x16x32_f16(qh[kk], kb0l, s0, 0, 0, 0);
        s0 = __builtin_amdgcn_mfma_f32_16x16x32_f16(ql[kk], kb0h, s0, 0, 0, 0);
        s1 = __builtin_amdgcn_mfma_f32_16x16x32_f16(qh[kk], kb1h, s1, 0, 0, 0);
        s1 = __builtin_amdgcn_mfma_f32_16x16x32_f16(qh[kk], kb1l, s1, 0, 0, 0);
        s1 = __builtin_amdgcn_mfma_f32_16x16x32_f16(ql[kk], kb1h, s1, 0, 0, 0);
      }
      const int qg = qt * 64 + wid * 16 + (lane >> 4) * 4;
      if (kt == ntw - 1) {
#pragma unroll
        for (int r = 0; r < 4; ++r) {
          int q = qg + r;
          int k0 = kt * 32 + l16, k1 = k0 + 16;
          s0[r] = (k0 <= q) ? s0[r] * scale : -1e30f;
          s1[r] = (k1 <= q) ? s1[r] * scale : -1e30f;
        }
      } else {
#pragma unroll
        for (int r = 0; r < 4; ++r) { s0[r] *= scale; s1[r] *= scale; }
      }
      float p0[4], p1[4], fr[4];
#pragma unroll
      for (int r = 0; r < 4; ++r) {
        float rm = fmaxf(s0[r], s1[r]);
        rm = fmaxf(rm, __shfl_xor(rm, 1));
        rm = fmaxf(rm, __shfl_xor(rm, 2));
        rm = fmaxf(rm, __shfl_xor(rm, 4));
        rm = fmaxf(rm, __shfl_xor(rm, 8));
        float mn = fmaxf(m_[r], rm);
        fr[r] = __expf(m_[r] - mn);
        m_[r] = mn;
        p0[r] = __expf(s0[r] - mn);
        p1[r] = __expf(s1[r] - mn);
        float rs = p0[r] + p1[r];
        rs += __shfl_xor(rs, 1);
        rs += __shfl_xor(rs, 2);
        rs += __shfl_xor(rs, 4);
        rs += __shfl_xor(rs, 8);
        l_[r] = l_[r] * fr[r] + rs;
      }
#pragma unroll
      for (int i = 0; i < 8; ++i)
#pragma unroll
        for (int r = 0; r < 4; ++r) of[i][r] *= fr[r];
#pragma unroll
      for (int r = 0; r < 4; ++r) {
        int q = (lane >> 4) * 4 + r;
        int swz = ((q >> 1) & 3) * 8;
        int c0 = l16, c1 = 16 + l16;
        _Float16 h0 = (_Float16)p0[r];
        _Float16 h1 = (_Float16)p1[r];
        sPh[wid * 512 + q * 32 + (c0 ^ swz)] = h0;
        sPl[wid * 512 + q * 32 + (c0 ^ swz)] = (_Float16)(p0[r] - (float)h0);
        sPh[wid * 512 + q * 32 + (c1 ^ swz)] = h1;
        sPl[wid * 512 + q * 32 + (c1 ^ swz)] = (_Float16)(p1[r] - (float)h1);
      }
      int pidxr = wid * 512 + l16 * 32 + ((lhi * 8) ^ (((l16 >> 1) & 3) * 8));
      f16x8 pah = *(const f16x8*)&sPh[pidxr];
      f16x8 pal = *(const f16x8*)&sPl[pidxr];
#pragma unroll
      for (int d16 = 0; d16 < 8; ++d16) {
        int d = d16 * 16 + l16;
        int vidx = d * 32 + ((lhi * 8) ^ (((d >> 1) & 3) * 8));
        f16x8 vbh = *(const f16x8*)&sVh[vidx];
        f16x8 vbl = *(const f16x8*)&sVl[vidx];
        f32x4 a = of[d16];
        a = __builtin_amdgcn_mfma_f32_16x16x32_f16(pah, vbh, a, 0, 0, 0);
        a = __builtin_amdgcn_mfma_f32_16x16x32_f16(pah, vbl, a, 0, 0, 0);
        a = __builtin_amdgcn_mfma_f32_16x16x32_f16(pal, vbh, a, 0, 0, 0);
        of[d16] = a;
      }
    }
  }
  float inv[4];
#pragma unroll
  for (int r = 0; r < 4; ++r) inv[r] = 1.f / l_[r];
  const int qg = qt * 64 + wid * 16 + (lane >> 4) * 4;
#pragma unroll
  for (int d16 = 0; d16 < 8; ++d16)
#pragma unroll
    for (int r = 0; r < 4; ++r) {
      float val = of[d16][r] * inv[r];
      size_t gi = qkbase + (size_t)(qg + r) * DMODEL + d16 * 16 + l16;
      O[gi] = val;
      Oh[gi] = (_Float16)val;
    }
}

// ---------------------------------------------------------------------------
extern "C" void kernel_launch(void* const* d_in, const int* in_sizes, int n_in,
                              void* d_out, int out_size, void* d_ws, size_t ws_size,
                              hipStream_t stream) {
  (void)in_sizes; (void)n_in; (void)out_size;
  const float* x        = (const float*)d_in[0];
  const float* Wr_in    = (const float*)d_in[2];
  const float* Wr_proc  = (const float*)d_in[3];
  const float* Wr_out   = (const float*)d_in[4];
  const float* WrO_in   = (const float*)d_in[5];
  const float* WrO_proc = (const float*)d_in[6];
  const float* WrO_out  = (const float*)d_in[7];
  const float* Wq_in    = (const float*)d_in[8];
  const float* vq       = (const float*)d_in[9];
  const float* Wq_out   = (const float*)d_in[10];
  const float* Wk_in    = (const float*)d_in[11];
  const float* vk       = (const float*)d_in[12];
  const float* Wk_out   = (const float*)d_in[13];
  const float* Wv_in    = (const float*)d_in[14];
  const float* vv       = (const float*)d_in[15];
  const float* Wv_out   = (const float*)d_in[16];
  const float* Wo_in    = (const float*)d_in[17];
  const float* vo       = (const float*)d_in[18];
  const float* Wo_out   = (const float*)d_in[19];

  char* wsbase = (char*)d_ws;
  size_t off = 0;
  auto carve = [&](size_t bytes) -> void* {
    void* r = wsbase + off;
    off = (off + bytes + 255) & ~(size_t)255;
    return r;
  };
  const size_t WBYTES = (size_t)KDIM * DMODEL * 2;     // 16.78 MB (B plane)
  const size_t PBYTES = (size_t)TOK * DMODEL * 2;      // 8.39 MB (A plane)
  const size_t HBYTES = (size_t)TOK * DMODEL * 4;      // 16.78 MB (fp32)
  _Float16* WTh = (_Float16*)carve(WBYTES);
  _Float16* WTl = (_Float16*)carve(WBYTES);
  _Float16* Xh  = (_Float16*)carve(PBYTES);
  _Float16* Xl  = (_Float16*)carve(PBYTES);   // contiguous after Xh
  _Float16* Hh  = (_Float16*)carve(PBYTES);
  _Float16* Hl  = (_Float16*)carve(PBYTES);
  float* P0 = (float*)carve(HBYTES);
  float* P1 = (float*)carve(HBYTES);
  float* P2 = (float*)carve(HBYTES);
  _Float16* Qph = (_Float16*)carve(PBYTES);
  _Float16* Qpl = (_Float16*)carve(PBYTES);   // contiguous after Qph
  _Float16* Kph = (_Float16*)carve(PBYTES);
  _Float16* Kpl = (_Float16*)carve(PBYTES);
  float* iw1 = (float*)carve((size_t)TOK * 8 * 4);
  float* ow1 = (float*)carve((size_t)TOK * 8 * 4);
  float* iw2 = (float*)carve((size_t)TOK * 8 * 4);
  float* ow2 = (float*)carve((size_t)TOK * 8 * 4);
  int* pi1 = (int*)carve((size_t)TOK * 3 * 4);
  int* pi2 = (int*)carve((size_t)TOK * 3 * 4);

  if (off > ws_size) {   // diagnosable failure instead of OOB abort
    hipMemsetAsync(d_out, 0, (size_t)out_size * 4, stream);
    return;
  }

  // Lifetime-disjoint aliases:
  float*    Pd  = (float*)d_out;               // 4th split-K partial (scratch)
  float*    PQ  = (float*)Qph;                 // Qph+Qpl contiguous = 16.78 MB
  float*    PX  = (float*)Xh;                  // Xh+Xl contiguous (post-attn)
  _Float16* Vth = WTh;                         // Vt planes live attn-only
  _Float16* Vtl = WTh + (size_t)TOK * DMODEL;
  float*    Ofp = P0;                          // O fp32 (router2 input)
  _Float16* Ohp = (_Float16*)P1;               // O hi plane (FAST gemm A)

  const dim3 blk(256);
  const dim3 gblk(512);
  const dim3 tgrid(KDIM / 64, DMODEL / 64);        // (128, 16)
  const dim3 ggrid(TOK / 256, DMODEL / 256, 4);    // (16, 4, 4) = 256 wgs
  const dim3 rgrid(TOK * DMODEL / (256 * 4));      // 4096
  const dim3 vgrid(S_LEN / 64, 2, 16);
  const dim3 agrid(S_LEN / 64, 16);

  // router 1 on x (fused X split)
  router_kernel<<<TOK, blk, 0, stream>>>(x, Wr_in, Wr_proc, Wr_out, iw1, ow1, pi1, Xh, Xl);

  // Q circuit
  transpose_split<<<tgrid, blk, 0, stream>>>(Wq_in, WTh, WTl);
  gemm_planes<false><<<ggrid, gblk, 0, stream>>>(Xh, Xl, iw1, WTh, WTl, P0, P1, P2, Pd);
  reflect4_kernel<<<TOK, blk, 0, stream>>>(P0, P1, P2, Pd, pi1, vq, Hh, Hl);
  transpose_split<<<tgrid, blk, 0, stream>>>(Wq_out, WTh, WTl);
  gemm_planes<false><<<ggrid, gblk, 0, stream>>>(Hh, Hl, ow1, WTh, WTl, P0, P1, P2, Pd);
  reduce4_planes<<<rgrid, blk, 0, stream>>>(P0, P1, P2, Pd, Qph, Qpl);

  // K circuit
  transpose_split<<<tgrid, blk, 0, stream>>>(Wk_in, WTh, WTl);
  gemm_planes<false><<<ggrid, gblk, 0, stream>>>(Xh, Xl, iw1, WTh, WTl, P0, P1, P2, Pd);
  reflect4_kernel<<<TOK, blk, 0, stream>>>(P0, P1, P2, Pd, pi1, vk, Hh, Hl);
  transpose_split<<<tgrid, blk, 0, stream>>>(Wk_out, WTh, WTl);
  gemm_planes<false><<<ggrid, gblk, 0, stream>>>(Hh, Hl, ow1, WTh, WTl, P0, P1, P2, Pd);
  reduce4_planes<<<rgrid, blk, 0, stream>>>(P0, P1, P2, Pd, Kph, Kpl);

  // V circuit
  transpose_split<<<tgrid, blk, 0, stream>>>(Wv_in, WTh, WTl);
  gemm_planes<false><<<ggrid, gblk, 0, stream>>>(Xh, Xl, iw1, WTh, WTl, P0, P1, P2, Pd);
  reflect4_kernel<<<TOK, blk, 0, stream>>>(P0, P1, P2, Pd, pi1, vv, Hh, Hl);
  transpose_split<<<tgrid, blk, 0, stream>>>(Wv_out, WTh, WTl);
  gemm_planes<false><<<ggrid, gblk, 0, stream>>>(Hh, Hl, ow1, WTh, WTl, P0, P1, P2, Pd);
  vtrans4_kernel<<<vgrid, blk, 0, stream>>>(P0, P1, P2, Pd, Vth, Vtl);

  // attention (Q/K/Vt planes -> O fp32 in P0, O hi plane in P1)
  attn_kernel<<<agrid, blk, 0, stream>>>(Qph, Qpl, Kph, Kpl, Vth, Vtl, Ofp, Ohp);

  // router 2 + final circuit (FAST gemms: 1-MFMA, hi planes, BK=64)
  router_kernel<<<TOK, blk, 0, stream>>>(Ofp, WrO_in, WrO_proc, WrO_out, iw2, ow2, pi2,
                                         nullptr, nullptr);
  transpose_split<<<tgrid, blk, 0, stream>>>(Wo_in, WTh, nullptr);  // hi only (FAST)
  gemm_planes<true><<<ggrid, gblk, 0, stream>>>(Ohp, Ohp, iw2, WTh, WTh, PX, P0, P2, Pd);
  reflect4_kernel<<<TOK, blk, 0, stream>>>(PX, P0, P2, Pd, pi2, vo, Hh, Hl);
  transpose_split<<<tgrid, blk, 0, stream>>>(Wo_out, WTh, nullptr); // hi only (FAST)
  gemm_planes<true><<<ggrid, gblk, 0, stream>>>(Hh, Hh, ow2, WTh, WTh, P0, P1, P2, PQ);
  reduce4_f32<<<rgrid, blk, 0, stream>>>(P0, P1, P2, PQ, (float*)d_out);
}